// Round 7
// baseline (242.627 us; speedup 1.0000x reference)
//
#include <hip/hip_runtime.h>

#define TT 1000
#define CC 3
#define HH 64
#define WW 64
#define HW 4096
#define CHW 12288
#define CHW4 3072            // CHW / 4
#define NCHUNK 50
#define CLEN 20              // NCHUNK*CLEN == TT
#define NCONVB 1000          // conv blocks: 1 block (256 thr) per t, thread = 4x4x3ch

typedef float f32x2 __attribute__((ext_vector_type(2)));
typedef float f32x4 __attribute__((ext_vector_type(4)));

// bf16 <-> f32 helpers (bf16 = top 16 bits of f32; RNE on encode)
__device__ __forceinline__ float bf2f(unsigned short u) {
    return __uint_as_float(((unsigned)u) << 16);
}
__device__ __forceinline__ unsigned short f2bf(float f) {
    unsigned u = __float_as_uint(f);
    return (unsigned short)((u + 0x7FFFu + ((u >> 16) & 1u)) >> 16);
}

// A[t,c,h,w] = bf16( et_coeff[t] * (conv3x3(xin[t])[c,h,w] + temb[tarr[t], c]) )
// One block per t; thread = (4-row quad, 4-col group) x 3 output channels.
// Packed f32 math (v_pk_fma_f32): acc pairs (k0,k1),(k2,k3); halo cols via shuffles.
// COPY_TAIL: blocks [NCONVB, NCONVB+12) instead copy xT -> out[0] (f32) and X[0] (bf16).
template <bool IN_BF16, bool COPY_TAIL>
__global__ __launch_bounds__(256, 4) void conv_kernel(const void* __restrict__ xin_v,
                                                      const float* __restrict__ cw,
                                                      const float* __restrict__ temb,
                                                      const int* __restrict__ tarr,
                                                      const float* __restrict__ ec,
                                                      unsigned short* __restrict__ A,
                                                      float* __restrict__ out0,
                                                      unsigned short* __restrict__ X0) {
    if (COPY_TAIL && blockIdx.x >= NCONVB) {
        int i = (blockIdx.x - NCONVB) * 256 + threadIdx.x;
        if (i < CHW4) {
            float4 v = ((const float4*)xin_v)[i];   // iter-1 input is x (f32); x[0] = xT
            ((float4*)out0)[i] = v;
            ushort4 u;
            u.x = f2bf(v.x); u.y = f2bf(v.y); u.z = f2bf(v.z); u.w = f2bf(v.w);
            *(ushort4*)(X0 + (size_t)i * 4) = u;
        }
        return;
    }

    int tid = threadIdx.x;
    int wi = tid & 15;
    int hr = tid >> 4;                          // 0..15
    int w0 = wi * 4;
    int h0 = hr * 4;
    int t  = blockIdx.x;                        // block-uniform

    const float* xtf = (const float*)xin_v + (size_t)t * CHW;
    const unsigned short* xtb = (const unsigned short*)xin_v + (size_t)t * CHW;

    f32x2 acc[4][CC][2];                        // [out-row][co][(k0,k1)|(k2,k3)]
    #pragma unroll
    for (int o = 0; o < 4; ++o)
        #pragma unroll
        for (int co = 0; co < CC; ++co) {
            acc[o][co][0] = (f32x2){0.f, 0.f};
            acc[o][co][1] = (f32x2){0.f, 0.f};
        }

    #pragma unroll
    for (int ch = 0; ch < CC; ++ch) {
        #pragma unroll
        for (int j = 0; j < 6; ++j) {           // input row h0-1+j
            int h = h0 - 1 + j;
            bool hv = (unsigned)h < (unsigned)HH;
            float4 M;
            if (IN_BF16) {
                ushort4 u = make_ushort4(0, 0, 0, 0);
                if (hv) u = *(const ushort4*)(xtb + ch * HW + h * WW + w0);
                M = make_float4(bf2f(u.x), bf2f(u.y), bf2f(u.z), bf2f(u.w));
            } else {
                M = hv ? *(const float4*)(xtf + ch * HW + h * WW + w0)
                       : make_float4(0.f, 0.f, 0.f, 0.f);
            }
            float left  = __shfl_up(M.w, 1);    if (wi == 0)  left  = 0.f;
            float right = __shfl_down(M.x, 1);  if (wi == 15) right = 0.f;
            // window pairs: win = {left, Mx, My, Mz, Mw, right}
            f32x2 P0 = {left, M.x};
            f32x2 P1 = {M.x,  M.y};
            f32x2 P2 = {M.y,  M.z};
            f32x2 P3 = {M.z,  M.w};
            f32x2 P4 = {M.w,  right};
            #pragma unroll
            for (int o = 0; o < 4; ++o) {
                const int kh = j - o;           // input row = (h0+o) + kh - 1
                if (kh >= 0 && kh <= 2) {
                    #pragma unroll
                    for (int co = 0; co < CC; ++co) {
                        float wa = cw[((co * CC + ch) * 3 + kh) * 3 + 0];
                        float wb = cw[((co * CC + ch) * 3 + kh) * 3 + 1];
                        float wc = cw[((co * CC + ch) * 3 + kh) * 3 + 2];
                        acc[o][co][0] += P0 * wa + P1 * wb + P2 * wc;
                        acc[o][co][1] += P2 * wa + P3 * wb + P4 * wc;
                    }
                }
            }
        }
    }

    float e = ec[t];
    int tr = tarr[t];
    #pragma unroll
    for (int o = 0; o < 4; ++o)
        #pragma unroll
        for (int co = 0; co < CC; ++co) {
            float b = temb[tr * CC + co];
            ushort4 v;
            v.x = f2bf(e * (acc[o][co][0].x + b));
            v.y = f2bf(e * (acc[o][co][0].y + b));
            v.z = f2bf(e * (acc[o][co][1].x + b));
            v.w = f2bf(e * (acc[o][co][1].y + b));
            *(ushort4*)(A + (size_t)t * CHW + co * HW + (h0 + o) * WW + w0) = v;
        }
}

// S[ch,pos] = sum of A over the chunk's CLEN t's (f32 accumulate from bf16)
__global__ __launch_bounds__(256) void chunk_sum_kernel(const unsigned short* __restrict__ A,
                                                        float4* __restrict__ S) {
    int ch = blockIdx.x / 12;                   // block-uniform
    int pos4 = (blockIdx.x % 12) * 256 + threadIdx.x;
    const unsigned short* p = A + (size_t)ch * CLEN * CHW + pos4 * 4;
    float4 acc = make_float4(0.f, 0.f, 0.f, 0.f);
    #pragma unroll
    for (int i = 0; i < CLEN; ++i) {
        ushort4 u = *(const ushort4*)(p + (size_t)i * CHW);
        acc.x += bf2f(u.x); acc.y += bf2f(u.y); acc.z += bf2f(u.z); acc.w += bf2f(u.w);
    }
    S[(size_t)ch * CHW4 + pos4] = acc;
}

// xt_next[t] = ar[t]*xT + epc[t]*(inline chunk-offset + local running sum)
// The exclusive chunk offset is computed inline: sum of S[j][pos4] for j < ch
// (column-local, coalesced, L2-resident) -- no scan dispatch needed.
// OUT_BF16: write bf16 state X_ws[t+1] (iters 1,2). Else f32 d_out[t+1] (iter 3).
template <bool OUT_BF16>
__global__ __launch_bounds__(256) void final_kernel(const unsigned short* __restrict__ A,
                                                    const float4* __restrict__ S,
                                                    const float4* __restrict__ xT,
                                                    const float* __restrict__ ar,
                                                    const float* __restrict__ epc,
                                                    void* __restrict__ out_v) {
    int ch = blockIdx.x / 12;                   // block-uniform
    int pos4 = (blockIdx.x % 12) * 256 + threadIdx.x;

    // inline exclusive prefix over chunk sums (4 independent partials for ILP)
    float4 a0 = make_float4(0.f, 0.f, 0.f, 0.f);
    float4 a1 = make_float4(0.f, 0.f, 0.f, 0.f);
    float4 a2 = make_float4(0.f, 0.f, 0.f, 0.f);
    float4 a3 = make_float4(0.f, 0.f, 0.f, 0.f);
    int j = 0;
    for (; j + 4 <= ch; j += 4) {               // block-uniform trip count
        float4 v0 = S[(size_t)(j + 0) * CHW4 + pos4];
        float4 v1 = S[(size_t)(j + 1) * CHW4 + pos4];
        float4 v2 = S[(size_t)(j + 2) * CHW4 + pos4];
        float4 v3 = S[(size_t)(j + 3) * CHW4 + pos4];
        a0.x += v0.x; a0.y += v0.y; a0.z += v0.z; a0.w += v0.w;
        a1.x += v1.x; a1.y += v1.y; a1.z += v1.z; a1.w += v1.w;
        a2.x += v2.x; a2.y += v2.y; a2.z += v2.z; a2.w += v2.w;
        a3.x += v3.x; a3.y += v3.y; a3.z += v3.z; a3.w += v3.w;
    }
    for (; j < ch; ++j) {
        float4 v = S[(size_t)j * CHW4 + pos4];
        a0.x += v.x; a0.y += v.y; a0.z += v.z; a0.w += v.w;
    }
    float4 acc = make_float4((a0.x + a1.x) + (a2.x + a3.x),
                             (a0.y + a1.y) + (a2.y + a3.y),
                             (a0.z + a1.z) + (a2.z + a3.z),
                             (a0.w + a1.w) + (a2.w + a3.w));

    float4 xv = xT[pos4];
    const unsigned short* p = A + (size_t)ch * CLEN * CHW + pos4 * 4;
    float* qf = (float*)out_v + ((size_t)(ch * CLEN + 1) * CHW4 + pos4) * 4;
    unsigned short* qb = (unsigned short*)out_v + ((size_t)(ch * CLEN + 1) * CHW4 + pos4) * 4;
    #pragma unroll
    for (int i = 0; i < CLEN; ++i) {
        int t = ch * CLEN + i;                  // block-uniform -> s_load
        ushort4 u = *(const ushort4*)(p + (size_t)i * CHW);
        acc.x += bf2f(u.x); acc.y += bf2f(u.y); acc.z += bf2f(u.z); acc.w += bf2f(u.w);
        float a = ar[t], e = epc[t];
        float4 r = make_float4(a * xv.x + e * acc.x, a * xv.y + e * acc.y,
                               a * xv.z + e * acc.z, a * xv.w + e * acc.w);
        if (OUT_BF16) {
            ushort4 ub;
            ub.x = f2bf(r.x); ub.y = f2bf(r.y); ub.z = f2bf(r.z); ub.w = f2bf(r.w);
            *(ushort4*)(qb + (size_t)i * CHW) = ub;
        } else {
            f32x4 rv = {r.x, r.y, r.z, r.w};    // ext_vector: valid nontemporal operand
            __builtin_nontemporal_store(rv, (f32x4*)(qf + (size_t)i * CHW));
        }
    }
}

extern "C" void kernel_launch(void* const* d_in, const int* in_sizes, int n_in,
                              void* d_out, int out_size, void* d_ws, size_t ws_size,
                              hipStream_t stream) {
    const float* x    = (const float*)d_in[0];   // (T+1, C, H, W)
    const int*   tarr = (const int*)  d_in[1];   // (T,)
    const float* ar   = (const float*)d_in[2];   // (T,1,1,1)
    const float* ec   = (const float*)d_in[3];   // (T,1,1,1)
    const float* epc  = (const float*)d_in[4];   // (T,1,1,1)
    const float* cw   = (const float*)d_in[5];   // (C,C,3,3)
    const float* temb = (const float*)d_in[6];   // (T,C)
    float* out = (float*)d_out;                  // (T+1, C, H, W)

    unsigned short* A = (unsigned short*)d_ws;      // TT*CHW bf16 (24.6 MB)
    float* S = (float*)(A + (size_t)TT * CHW);      // NCHUNK*CHW f32 (2.46 MB)
    unsigned short* X = (unsigned short*)(S + (size_t)NCHUNK * CHW);  // (TT+1)*CHW bf16 state

    // iter 1: f32 x in -> bf16 X state out; tail blocks copy out[0]=xT, X[0]=bf16(xT)
    conv_kernel<false, true><<<NCONVB + 12, 256, 0, stream>>>(x, cw, temb, tarr, ec, A, out, X);
    chunk_sum_kernel<<<NCHUNK * 12, 256, 0, stream>>>(A, (float4*)S);
    final_kernel<true><<<NCHUNK * 12, 256, 0, stream>>>(A, (const float4*)S,
                                                        (const float4*)x, ar, epc, X);

    // iter 2: bf16 X in -> bf16 X out
    conv_kernel<true, false><<<NCONVB, 256, 0, stream>>>(X, cw, temb, tarr, ec, A, out, X);
    chunk_sum_kernel<<<NCHUNK * 12, 256, 0, stream>>>(A, (float4*)S);
    final_kernel<true><<<NCHUNK * 12, 256, 0, stream>>>(A, (const float4*)S,
                                                        (const float4*)x, ar, epc, X);

    // iter 3: bf16 X in -> f32 d_out
    conv_kernel<true, false><<<NCONVB, 256, 0, stream>>>(X, cw, temb, tarr, ec, A, out, X);
    chunk_sum_kernel<<<NCHUNK * 12, 256, 0, stream>>>(A, (float4*)S);
    final_kernel<false><<<NCHUNK * 12, 256, 0, stream>>>(A, (const float4*)S,
                                                         (const float4*)x, ar, epc, out);
}

// Round 8
// 213.848 us; speedup vs baseline: 1.1346x; 1.1346x over previous
//
#include <hip/hip_runtime.h>

#define TT 1000
#define CC 3
#define HH 64
#define WW 64
#define HW 4096
#define CHW 12288
#define CHW4 3072            // CHW / 4
#define NCHUNK 50
#define CLEN 20              // NCHUNK*CLEN == TT
#define NCONVB 2000          // conv blocks (512 threads per t -> 2 blocks/t)

typedef float f32x4 __attribute__((ext_vector_type(4)));

// bf16 <-> f32 helpers (bf16 = top 16 bits of f32; RNE on encode)
__device__ __forceinline__ float bf2f(unsigned short u) {
    return __uint_as_float(((unsigned)u) << 16);
}
__device__ __forceinline__ unsigned short f2bf(float f) {
    unsigned u = __float_as_uint(f);
    return (unsigned short)((u + 0x7FFFu + ((u >> 16) & 1u)) >> 16);
}

// A[t,c,h,w] = bf16( et_coeff[t] * (conv3x3(xin[t])[c,h,w] + temb[tarr[t], c]) )
// thread = (t, 2-row pair, 4-col group); 3 output channels share all loads.
// Halo columns via wave shuffles. Input either f32 (iter 1) or bf16 state.
// XCD swizzle: b -> (xcd=b&7, half=(b>>3)&1, k=b>>4, t=xcd*125+k). Bijective over
// 2000 = 8*2*125; both half-image blocks of a t land on one XCD (L2 halo/t sharing),
// and each XCD owns a contiguous 125-t range (~3MB A slice fits its 4MB L2).
// COPY_TAIL: blocks [NCONVB, NCONVB+12) instead copy xT -> out[0] (f32) and X[0] (bf16).
template <bool IN_BF16, bool COPY_TAIL>
__global__ __launch_bounds__(256) void conv_kernel(const void* __restrict__ xin_v,
                                                   const float* __restrict__ cw,
                                                   const float* __restrict__ temb,
                                                   const int* __restrict__ tarr,
                                                   const float* __restrict__ ec,
                                                   unsigned short* __restrict__ A,
                                                   float* __restrict__ out0,
                                                   unsigned short* __restrict__ X0) {
    if (COPY_TAIL && blockIdx.x >= NCONVB) {
        int i = (blockIdx.x - NCONVB) * 256 + threadIdx.x;
        if (i < CHW4) {
            float4 v = ((const float4*)xin_v)[i];   // iter-1 input is x (f32); x[0] = xT
            ((float4*)out0)[i] = v;
            ushort4 u;
            u.x = f2bf(v.x); u.y = f2bf(v.y); u.z = f2bf(v.z); u.w = f2bf(v.w);
            *(ushort4*)(X0 + (size_t)i * 4) = u;
        }
        return;
    }

    int b = blockIdx.x;
    int xcd  = b & 7;
    int half = (b >> 3) & 1;
    int k    = b >> 4;                          // 0..124
    int t    = xcd * 125 + k;                   // block-uniform
    int il   = half * 256 + (int)threadIdx.x;   // 0..511 within t
    int wi = il & 15;
    int hp = il >> 4;                           // 0..31
    int h0 = hp * 2;
    int w0 = wi * 4;

    const float* xtf = (const float*)xin_v + (size_t)t * CHW;
    const unsigned short* xtb = (const unsigned short*)xin_v + (size_t)t * CHW;

    float acc[2][CC][4];
    #pragma unroll
    for (int o = 0; o < 2; ++o)
        #pragma unroll
        for (int co = 0; co < CC; ++co)
            #pragma unroll
            for (int kk = 0; kk < 4; ++kk) acc[o][co][kk] = 0.f;

    #pragma unroll
    for (int ch = 0; ch < CC; ++ch) {
        #pragma unroll
        for (int j = 0; j < 4; ++j) {           // input row h0-1+j
            int h = h0 - 1 + j;
            bool hv = (unsigned)h < (unsigned)HH;
            float4 M;
            if (IN_BF16) {
                ushort4 u = make_ushort4(0, 0, 0, 0);
                if (hv) u = *(const ushort4*)(xtb + ch * HW + h * WW + w0);
                M = make_float4(bf2f(u.x), bf2f(u.y), bf2f(u.z), bf2f(u.w));
            } else {
                M = hv ? *(const float4*)(xtf + ch * HW + h * WW + w0)
                       : make_float4(0.f, 0.f, 0.f, 0.f);
            }
            float left  = __shfl_up(M.w, 1);    if (wi == 0)  left  = 0.f;
            float right = __shfl_down(M.x, 1);  if (wi == 15) right = 0.f;
            float win[6] = {left, M.x, M.y, M.z, M.w, right};
            #pragma unroll
            for (int o = 0; o < 2; ++o) {
                const int kh = j - o;           // input row = (h0+o) + kh - 1
                if (kh >= 0 && kh <= 2) {
                    #pragma unroll
                    for (int co = 0; co < CC; ++co) {
                        float wa = cw[((co * CC + ch) * 3 + kh) * 3 + 0];
                        float wb = cw[((co * CC + ch) * 3 + kh) * 3 + 1];
                        float wc = cw[((co * CC + ch) * 3 + kh) * 3 + 2];
                        #pragma unroll
                        for (int kk = 0; kk < 4; ++kk)
                            acc[o][co][kk] += win[kk] * wa + win[kk + 1] * wb + win[kk + 2] * wc;
                    }
                }
            }
        }
    }

    float e = ec[t];
    int tr = tarr[t];
    #pragma unroll
    for (int o = 0; o < 2; ++o)
        #pragma unroll
        for (int co = 0; co < CC; ++co) {
            float bb = temb[tr * CC + co];
            ushort4 v;
            v.x = f2bf(e * (acc[o][co][0] + bb));
            v.y = f2bf(e * (acc[o][co][1] + bb));
            v.z = f2bf(e * (acc[o][co][2] + bb));
            v.w = f2bf(e * (acc[o][co][3] + bb));
            *(ushort4*)(A + (size_t)t * CHW + co * HW + (h0 + o) * WW + w0) = v;
        }
}

// S[ch,pos] = sum of A over the chunk's CLEN t's (f32 accumulate from bf16)
__global__ __launch_bounds__(256) void chunk_sum_kernel(const unsigned short* __restrict__ A,
                                                        float4* __restrict__ S) {
    int ch = blockIdx.x / 12;                   // block-uniform
    int pos4 = (blockIdx.x % 12) * 256 + threadIdx.x;
    const unsigned short* p = A + (size_t)ch * CLEN * CHW + pos4 * 4;
    float4 acc = make_float4(0.f, 0.f, 0.f, 0.f);
    #pragma unroll
    for (int i = 0; i < CLEN; ++i) {
        ushort4 u = *(const ushort4*)(p + (size_t)i * CHW);
        acc.x += bf2f(u.x); acc.y += bf2f(u.y); acc.z += bf2f(u.z); acc.w += bf2f(u.w);
    }
    S[(size_t)ch * CHW4 + pos4] = acc;
}

// xt_next[t] = ar[t]*xT + epc[t]*(inline chunk-offset + local running sum)
// The exclusive chunk offset is computed inline: sum of S[j][pos4] for j < ch
// (column-local, coalesced, L2-resident) -- no scan dispatch needed.
// OUT_BF16: write bf16 state X_ws[t+1] (iters 1,2). Else f32 d_out[t+1] (iter 3,
// nontemporal: out is never re-read, keep it from evicting A/X in L2).
template <bool OUT_BF16>
__global__ __launch_bounds__(256) void final_kernel(const unsigned short* __restrict__ A,
                                                    const float4* __restrict__ S,
                                                    const float4* __restrict__ xT,
                                                    const float* __restrict__ ar,
                                                    const float* __restrict__ epc,
                                                    void* __restrict__ out_v) {
    int ch = blockIdx.x / 12;                   // block-uniform
    int pos4 = (blockIdx.x % 12) * 256 + threadIdx.x;

    // inline exclusive prefix over chunk sums (4 independent partials for ILP)
    float4 a0 = make_float4(0.f, 0.f, 0.f, 0.f);
    float4 a1 = make_float4(0.f, 0.f, 0.f, 0.f);
    float4 a2 = make_float4(0.f, 0.f, 0.f, 0.f);
    float4 a3 = make_float4(0.f, 0.f, 0.f, 0.f);
    int j = 0;
    for (; j + 4 <= ch; j += 4) {               // block-uniform trip count
        float4 v0 = S[(size_t)(j + 0) * CHW4 + pos4];
        float4 v1 = S[(size_t)(j + 1) * CHW4 + pos4];
        float4 v2 = S[(size_t)(j + 2) * CHW4 + pos4];
        float4 v3 = S[(size_t)(j + 3) * CHW4 + pos4];
        a0.x += v0.x; a0.y += v0.y; a0.z += v0.z; a0.w += v0.w;
        a1.x += v1.x; a1.y += v1.y; a1.z += v1.z; a1.w += v1.w;
        a2.x += v2.x; a2.y += v2.y; a2.z += v2.z; a2.w += v2.w;
        a3.x += v3.x; a3.y += v3.y; a3.z += v3.z; a3.w += v3.w;
    }
    for (; j < ch; ++j) {
        float4 v = S[(size_t)j * CHW4 + pos4];
        a0.x += v.x; a0.y += v.y; a0.z += v.z; a0.w += v.w;
    }
    float4 acc = make_float4((a0.x + a1.x) + (a2.x + a3.x),
                             (a0.y + a1.y) + (a2.y + a3.y),
                             (a0.z + a1.z) + (a2.z + a3.z),
                             (a0.w + a1.w) + (a2.w + a3.w));

    float4 xv = xT[pos4];
    const unsigned short* p = A + (size_t)ch * CLEN * CHW + pos4 * 4;
    float* qf = (float*)out_v + ((size_t)(ch * CLEN + 1) * CHW4 + pos4) * 4;
    unsigned short* qb = (unsigned short*)out_v + ((size_t)(ch * CLEN + 1) * CHW4 + pos4) * 4;
    #pragma unroll
    for (int i = 0; i < CLEN; ++i) {
        int t = ch * CLEN + i;                  // block-uniform -> s_load
        ushort4 u = *(const ushort4*)(p + (size_t)i * CHW);
        acc.x += bf2f(u.x); acc.y += bf2f(u.y); acc.z += bf2f(u.z); acc.w += bf2f(u.w);
        float a = ar[t], e = epc[t];
        float4 r = make_float4(a * xv.x + e * acc.x, a * xv.y + e * acc.y,
                               a * xv.z + e * acc.z, a * xv.w + e * acc.w);
        if (OUT_BF16) {
            ushort4 ub;
            ub.x = f2bf(r.x); ub.y = f2bf(r.y); ub.z = f2bf(r.z); ub.w = f2bf(r.w);
            *(ushort4*)(qb + (size_t)i * CHW) = ub;
        } else {
            f32x4 rv = {r.x, r.y, r.z, r.w};    // ext_vector: valid nontemporal operand
            __builtin_nontemporal_store(rv, (f32x4*)(qf + (size_t)i * CHW));
        }
    }
}

extern "C" void kernel_launch(void* const* d_in, const int* in_sizes, int n_in,
                              void* d_out, int out_size, void* d_ws, size_t ws_size,
                              hipStream_t stream) {
    const float* x    = (const float*)d_in[0];   // (T+1, C, H, W)
    const int*   tarr = (const int*)  d_in[1];   // (T,)
    const float* ar   = (const float*)d_in[2];   // (T,1,1,1)
    const float* ec   = (const float*)d_in[3];   // (T,1,1,1)
    const float* epc  = (const float*)d_in[4];   // (T,1,1,1)
    const float* cw   = (const float*)d_in[5];   // (C,C,3,3)
    const float* temb = (const float*)d_in[6];   // (T,C)
    float* out = (float*)d_out;                  // (T+1, C, H, W)

    unsigned short* A = (unsigned short*)d_ws;      // TT*CHW bf16 (24.6 MB)
    float* S = (float*)(A + (size_t)TT * CHW);      // NCHUNK*CHW f32 (2.46 MB)
    unsigned short* X = (unsigned short*)(S + (size_t)NCHUNK * CHW);  // (TT+1)*CHW bf16 state

    // iter 1: f32 x in -> bf16 X state out; tail blocks copy out[0]=xT, X[0]=bf16(xT)
    conv_kernel<false, true><<<NCONVB + 12, 256, 0, stream>>>(x, cw, temb, tarr, ec, A, out, X);
    chunk_sum_kernel<<<NCHUNK * 12, 256, 0, stream>>>(A, (float4*)S);
    final_kernel<true><<<NCHUNK * 12, 256, 0, stream>>>(A, (const float4*)S,
                                                        (const float4*)x, ar, epc, X);

    // iter 2: bf16 X in -> bf16 X out
    conv_kernel<true, false><<<NCONVB, 256, 0, stream>>>(X, cw, temb, tarr, ec, A, out, X);
    chunk_sum_kernel<<<NCHUNK * 12, 256, 0, stream>>>(A, (float4*)S);
    final_kernel<true><<<NCHUNK * 12, 256, 0, stream>>>(A, (const float4*)S,
                                                        (const float4*)x, ar, epc, X);

    // iter 3: bf16 X in -> f32 d_out
    conv_kernel<true, false><<<NCONVB, 256, 0, stream>>>(X, cw, temb, tarr, ec, A, out, X);
    chunk_sum_kernel<<<NCHUNK * 12, 256, 0, stream>>>(A, (float4*)S);
    final_kernel<false><<<NCHUNK * 12, 256, 0, stream>>>(A, (const float4*)S,
                                                         (const float4*)x, ar, epc, out);
}

// Round 9
// 212.031 us; speedup vs baseline: 1.1443x; 1.0086x over previous
//
#include <hip/hip_runtime.h>

#define TT 1000
#define CC 3
#define HH 64
#define WW 64
#define HW 4096
#define CHW 12288
#define CHW4 3072            // CHW / 4
#define CHW8 1536            // CHW / 8
#define NCHUNK 50
#define CLEN 20              // NCHUNK*CLEN == TT
#define NCONVB 2000          // conv blocks (512 threads per t -> 2 blocks/t)

// bf16 <-> f32 helpers (bf16 = top 16 bits of f32; RNE on encode)
__device__ __forceinline__ float bf2f(unsigned short u) {
    return __uint_as_float(((unsigned)u) << 16);
}
__device__ __forceinline__ unsigned short f2bf(float f) {
    unsigned u = __float_as_uint(f);
    return (unsigned short)((u + 0x7FFFu + ((u >> 16) & 1u)) >> 16);
}
// decode a packed u32 (2 bf16) -> 2 f32
__device__ __forceinline__ float bflo(unsigned w) { return __uint_as_float(w << 16); }
__device__ __forceinline__ float bfhi(unsigned w) { return __uint_as_float(w & 0xFFFF0000u); }
// encode 2 f32 -> packed u32 (2 bf16: lo from f0, hi from f1)
__device__ __forceinline__ unsigned pk2bf(float f0, float f1) {
    return ((unsigned)f2bf(f0)) | (((unsigned)f2bf(f1)) << 16);
}

// A[t,c,h,w] = bf16( et_coeff[t] * (conv3x3(xin[t])[c,h,w] + temb[tarr[t], c]) )
// thread = (t, 2-row pair, 4-col group); 3 output channels share all loads.
// Halo columns via wave shuffles. Input either f32 (iter 1) or bf16 state.
// COPY_TAIL: blocks [NCONVB, NCONVB+12) instead copy xT -> out[0] (f32) and X[0] (bf16).
template <bool IN_BF16, bool COPY_TAIL>
__global__ __launch_bounds__(256) void conv_kernel(const void* __restrict__ xin_v,
                                                   const float* __restrict__ cw,
                                                   const float* __restrict__ temb,
                                                   const int* __restrict__ tarr,
                                                   const float* __restrict__ ec,
                                                   unsigned short* __restrict__ A,
                                                   float* __restrict__ out0,
                                                   unsigned short* __restrict__ X0) {
    if (COPY_TAIL && blockIdx.x >= NCONVB) {
        int i = (blockIdx.x - NCONVB) * 256 + threadIdx.x;
        if (i < CHW4) {
            float4 v = ((const float4*)xin_v)[i];   // iter-1 input is x (f32); x[0] = xT
            ((float4*)out0)[i] = v;
            ushort4 u;
            u.x = f2bf(v.x); u.y = f2bf(v.y); u.z = f2bf(v.z); u.w = f2bf(v.w);
            *(ushort4*)(X0 + (size_t)i * 4) = u;
        }
        return;
    }

    int idx = blockIdx.x * 256 + threadIdx.x;   // TT*32*16 = 512000 exactly
    int wi = idx & 15;
    int hp = (idx >> 4) & 31;
    int t  = idx >> 9;                          // block-uniform (2 blocks/t)
    int h0 = hp * 2;
    int w0 = wi * 4;

    const float* xtf = (const float*)xin_v + (size_t)t * CHW;
    const unsigned short* xtb = (const unsigned short*)xin_v + (size_t)t * CHW;

    float acc[2][CC][4];
    #pragma unroll
    for (int o = 0; o < 2; ++o)
        #pragma unroll
        for (int co = 0; co < CC; ++co)
            #pragma unroll
            for (int k = 0; k < 4; ++k) acc[o][co][k] = 0.f;

    #pragma unroll
    for (int ch = 0; ch < CC; ++ch) {
        #pragma unroll
        for (int j = 0; j < 4; ++j) {           // input row h0-1+j
            int h = h0 - 1 + j;
            bool hv = (unsigned)h < (unsigned)HH;
            float4 M;
            if (IN_BF16) {
                ushort4 u = make_ushort4(0, 0, 0, 0);
                if (hv) u = *(const ushort4*)(xtb + ch * HW + h * WW + w0);
                M = make_float4(bf2f(u.x), bf2f(u.y), bf2f(u.z), bf2f(u.w));
            } else {
                M = hv ? *(const float4*)(xtf + ch * HW + h * WW + w0)
                       : make_float4(0.f, 0.f, 0.f, 0.f);
            }
            float left  = __shfl_up(M.w, 1);    if (wi == 0)  left  = 0.f;
            float right = __shfl_down(M.x, 1);  if (wi == 15) right = 0.f;
            float win[6] = {left, M.x, M.y, M.z, M.w, right};
            #pragma unroll
            for (int o = 0; o < 2; ++o) {
                const int kh = j - o;           // input row = (h0+o) + kh - 1
                if (kh >= 0 && kh <= 2) {
                    #pragma unroll
                    for (int co = 0; co < CC; ++co) {
                        float wa = cw[((co * CC + ch) * 3 + kh) * 3 + 0];
                        float wb = cw[((co * CC + ch) * 3 + kh) * 3 + 1];
                        float wc = cw[((co * CC + ch) * 3 + kh) * 3 + 2];
                        #pragma unroll
                        for (int k = 0; k < 4; ++k)
                            acc[o][co][k] += win[k] * wa + win[k + 1] * wb + win[k + 2] * wc;
                    }
                }
            }
        }
    }

    float e = ec[t];
    int tr = tarr[t];
    #pragma unroll
    for (int o = 0; o < 2; ++o)
        #pragma unroll
        for (int co = 0; co < CC; ++co) {
            float b = temb[tr * CC + co];
            ushort4 v;
            v.x = f2bf(e * (acc[o][co][0] + b));
            v.y = f2bf(e * (acc[o][co][1] + b));
            v.z = f2bf(e * (acc[o][co][2] + b));
            v.w = f2bf(e * (acc[o][co][3] + b));
            *(ushort4*)(A + (size_t)t * CHW + co * HW + (h0 + o) * WW + w0) = v;
        }
}

// S[ch, pos] = sum of A over the chunk's CLEN t's (f32 accumulate from bf16).
// Widened: thread owns 8 elems; A loads are uint4 (16 B/lane, 8 bf16).
// Per-element accumulation order identical to the 4-wide version (t-order).
__global__ __launch_bounds__(256) void chunk_sum_kernel(const unsigned short* __restrict__ A,
                                                        float* __restrict__ S) {
    int ch = blockIdx.x / 6;                    // block-uniform
    int pos8 = (blockIdx.x % 6) * 256 + threadIdx.x;
    const uint4* p = (const uint4*)(A + (size_t)ch * CLEN * CHW + (size_t)pos8 * 8);
    float acc[8];
    #pragma unroll
    for (int k = 0; k < 8; ++k) acc[k] = 0.f;
    #pragma unroll
    for (int i = 0; i < CLEN; ++i) {
        uint4 u = p[(size_t)i * CHW8];
        acc[0] += bflo(u.x); acc[1] += bfhi(u.x);
        acc[2] += bflo(u.y); acc[3] += bfhi(u.y);
        acc[4] += bflo(u.z); acc[5] += bfhi(u.z);
        acc[6] += bflo(u.w); acc[7] += bfhi(u.w);
    }
    float* s = S + (size_t)ch * CHW + (size_t)pos8 * 8;
    *(float4*)(s + 0) = make_float4(acc[0], acc[1], acc[2], acc[3]);
    *(float4*)(s + 4) = make_float4(acc[4], acc[5], acc[6], acc[7]);
}

// xt_next[t] = ar[t]*xT + epc[t]*(inline chunk-offset + local running sum)
// Exclusive chunk offset computed inline from S (column-local, L2-resident).
// Widened to 8 elems/thread; prefix grouping (4-way ILP, (a0+a1)+(a2+a3))
// identical per element to the 4-wide version -> bit-identical results.
// OUT_BF16: write bf16 state X_ws[t+1] (iters 1,2). Else f32 d_out[t+1] (iter 3).
template <bool OUT_BF16>
__global__ __launch_bounds__(256) void final_kernel(const unsigned short* __restrict__ A,
                                                    const float* __restrict__ S,
                                                    const float* __restrict__ xT,
                                                    const float* __restrict__ ar,
                                                    const float* __restrict__ epc,
                                                    void* __restrict__ out_v) {
    int ch = blockIdx.x / 6;                    // block-uniform
    int pos8 = (blockIdx.x % 6) * 256 + threadIdx.x;

    float a0[8], a1[8], a2[8], a3[8];
    #pragma unroll
    for (int k = 0; k < 8; ++k) { a0[k] = 0.f; a1[k] = 0.f; a2[k] = 0.f; a3[k] = 0.f; }
    const float* Sp = S + (size_t)pos8 * 8;
    int j = 0;
    for (; j + 4 <= ch; j += 4) {               // block-uniform trip count
        #pragma unroll
        for (int g = 0; g < 4; ++g) {
            const float* q = Sp + (size_t)(j + g) * CHW;
            float4 lo = *(const float4*)(q + 0);
            float4 hi = *(const float4*)(q + 4);
            float* ag = (g == 0) ? a0 : (g == 1) ? a1 : (g == 2) ? a2 : a3;
            ag[0] += lo.x; ag[1] += lo.y; ag[2] += lo.z; ag[3] += lo.w;
            ag[4] += hi.x; ag[5] += hi.y; ag[6] += hi.z; ag[7] += hi.w;
        }
    }
    for (; j < ch; ++j) {
        const float* q = Sp + (size_t)j * CHW;
        float4 lo = *(const float4*)(q + 0);
        float4 hi = *(const float4*)(q + 4);
        a0[0] += lo.x; a0[1] += lo.y; a0[2] += lo.z; a0[3] += lo.w;
        a0[4] += hi.x; a0[5] += hi.y; a0[6] += hi.z; a0[7] += hi.w;
    }
    float acc[8];
    #pragma unroll
    for (int k = 0; k < 8; ++k) acc[k] = (a0[k] + a1[k]) + (a2[k] + a3[k]);

    float xv[8];
    {
        const float* q = xT + (size_t)pos8 * 8;
        float4 lo = *(const float4*)(q + 0);
        float4 hi = *(const float4*)(q + 4);
        xv[0] = lo.x; xv[1] = lo.y; xv[2] = lo.z; xv[3] = lo.w;
        xv[4] = hi.x; xv[5] = hi.y; xv[6] = hi.z; xv[7] = hi.w;
    }

    const uint4* p = (const uint4*)(A + (size_t)ch * CLEN * CHW + (size_t)pos8 * 8);
    size_t qoff = (size_t)(ch * CLEN + 1) * CHW + (size_t)pos8 * 8;   // element offset
    float* qf = (float*)out_v + qoff;
    unsigned short* qb = (unsigned short*)out_v + qoff;
    #pragma unroll
    for (int i = 0; i < CLEN; ++i) {
        int t = ch * CLEN + i;                  // block-uniform -> s_load
        uint4 u = p[(size_t)i * CHW8];
        acc[0] += bflo(u.x); acc[1] += bfhi(u.x);
        acc[2] += bflo(u.y); acc[3] += bfhi(u.y);
        acc[4] += bflo(u.z); acc[5] += bfhi(u.z);
        acc[6] += bflo(u.w); acc[7] += bfhi(u.w);
        float a = ar[t], e = epc[t];
        float r[8];
        #pragma unroll
        for (int k = 0; k < 8; ++k) r[k] = a * xv[k] + e * acc[k];
        if (OUT_BF16) {
            uint4 ub;
            ub.x = pk2bf(r[0], r[1]); ub.y = pk2bf(r[2], r[3]);
            ub.z = pk2bf(r[4], r[5]); ub.w = pk2bf(r[6], r[7]);
            *(uint4*)(qb + (size_t)i * CHW) = ub;
        } else {
            float* q = qf + (size_t)i * CHW;
            *(float4*)(q + 0) = make_float4(r[0], r[1], r[2], r[3]);
            *(float4*)(q + 4) = make_float4(r[4], r[5], r[6], r[7]);
        }
    }
}

extern "C" void kernel_launch(void* const* d_in, const int* in_sizes, int n_in,
                              void* d_out, int out_size, void* d_ws, size_t ws_size,
                              hipStream_t stream) {
    const float* x    = (const float*)d_in[0];   // (T+1, C, H, W)
    const int*   tarr = (const int*)  d_in[1];   // (T,)
    const float* ar   = (const float*)d_in[2];   // (T,1,1,1)
    const float* ec   = (const float*)d_in[3];   // (T,1,1,1)
    const float* epc  = (const float*)d_in[4];   // (T,1,1,1)
    const float* cw   = (const float*)d_in[5];   // (C,C,3,3)
    const float* temb = (const float*)d_in[6];   // (T,C)
    float* out = (float*)d_out;                  // (T+1, C, H, W)

    unsigned short* A = (unsigned short*)d_ws;      // TT*CHW bf16 (24.6 MB)
    float* S = (float*)(A + (size_t)TT * CHW);      // NCHUNK*CHW f32 (2.46 MB)
    unsigned short* X = (unsigned short*)(S + (size_t)NCHUNK * CHW);  // (TT+1)*CHW bf16 state

    // iter 1: f32 x in -> bf16 X state out; tail blocks copy out[0]=xT, X[0]=bf16(xT)
    conv_kernel<false, true><<<NCONVB + 12, 256, 0, stream>>>(x, cw, temb, tarr, ec, A, out, X);
    chunk_sum_kernel<<<NCHUNK * 6, 256, 0, stream>>>(A, S);
    final_kernel<true><<<NCHUNK * 6, 256, 0, stream>>>(A, S, x, ar, epc, X);

    // iter 2: bf16 X in -> bf16 X out
    conv_kernel<true, false><<<NCONVB, 256, 0, stream>>>(X, cw, temb, tarr, ec, A, out, X);
    chunk_sum_kernel<<<NCHUNK * 6, 256, 0, stream>>>(A, S);
    final_kernel<true><<<NCHUNK * 6, 256, 0, stream>>>(A, S, x, ar, epc, X);

    // iter 3: bf16 X in -> f32 d_out
    conv_kernel<true, false><<<NCONVB, 256, 0, stream>>>(X, cw, temb, tarr, ec, A, out, X);
    chunk_sum_kernel<<<NCHUNK * 6, 256, 0, stream>>>(A, S);
    final_kernel<false><<<NCHUNK * 6, 256, 0, stream>>>(A, S, x, ar, epc, out);
}

// Round 10
// 203.570 us; speedup vs baseline: 1.1919x; 1.0416x over previous
//
#include <hip/hip_runtime.h>

#define TT 1000
#define CC 3
#define HH 64
#define WW 64
#define HW 4096
#define CHW 12288
#define CHW4 3072            // CHW / 4
#define NCHUNK 50
#define CLEN 20              // NCHUNK*CLEN == TT
#define NCONVB 2000          // conv blocks (512 threads per t -> 2 blocks/t)

// bf16 <-> f32 helpers (bf16 = top 16 bits of f32; RNE on encode)
__device__ __forceinline__ float bf2f(unsigned short u) {
    return __uint_as_float(((unsigned)u) << 16);
}
__device__ __forceinline__ unsigned short f2bf(float f) {
    unsigned u = __float_as_uint(f);
    return (unsigned short)((u + 0x7FFFu + ((u >> 16) & 1u)) >> 16);
}

// A[t,c,h,w] = bf16( et_coeff[t] * (conv3x3(xin[t])[c,h,w] + temb[tarr[t], c]) )
// thread = (t, 2-row pair, 4-col group); 3 output channels share all loads.
// Halo columns via wave shuffles. Input either f32 (iter 1) or bf16 state.
// COPY_TAIL: blocks [NCONVB, NCONVB+12) instead copy xT -> out[0] (f32) and X[0] (bf16).
template <bool IN_BF16, bool COPY_TAIL>
__global__ __launch_bounds__(256) void conv_kernel(const void* __restrict__ xin_v,
                                                   const float* __restrict__ cw,
                                                   const float* __restrict__ temb,
                                                   const int* __restrict__ tarr,
                                                   const float* __restrict__ ec,
                                                   unsigned short* __restrict__ A,
                                                   float* __restrict__ out0,
                                                   unsigned short* __restrict__ X0) {
    if (COPY_TAIL && blockIdx.x >= NCONVB) {
        int i = (blockIdx.x - NCONVB) * 256 + threadIdx.x;
        if (i < CHW4) {
            float4 v = ((const float4*)xin_v)[i];   // iter-1 input is x (f32); x[0] = xT
            ((float4*)out0)[i] = v;
            ushort4 u;
            u.x = f2bf(v.x); u.y = f2bf(v.y); u.z = f2bf(v.z); u.w = f2bf(v.w);
            *(ushort4*)(X0 + (size_t)i * 4) = u;
        }
        return;
    }

    int idx = blockIdx.x * 256 + threadIdx.x;   // TT*32*16 = 512000 exactly
    int wi = idx & 15;
    int hp = (idx >> 4) & 31;
    int t  = idx >> 9;                          // block-uniform (2 blocks/t)
    int h0 = hp * 2;
    int w0 = wi * 4;

    const float* xtf = (const float*)xin_v + (size_t)t * CHW;
    const unsigned short* xtb = (const unsigned short*)xin_v + (size_t)t * CHW;

    float acc[2][CC][4];
    #pragma unroll
    for (int o = 0; o < 2; ++o)
        #pragma unroll
        for (int co = 0; co < CC; ++co)
            #pragma unroll
            for (int k = 0; k < 4; ++k) acc[o][co][k] = 0.f;

    #pragma unroll
    for (int ch = 0; ch < CC; ++ch) {
        #pragma unroll
        for (int j = 0; j < 4; ++j) {           // input row h0-1+j
            int h = h0 - 1 + j;
            bool hv = (unsigned)h < (unsigned)HH;
            float4 M;
            if (IN_BF16) {
                ushort4 u = make_ushort4(0, 0, 0, 0);
                if (hv) u = *(const ushort4*)(xtb + ch * HW + h * WW + w0);
                M = make_float4(bf2f(u.x), bf2f(u.y), bf2f(u.z), bf2f(u.w));
            } else {
                M = hv ? *(const float4*)(xtf + ch * HW + h * WW + w0)
                       : make_float4(0.f, 0.f, 0.f, 0.f);
            }
            float left  = __shfl_up(M.w, 1);    if (wi == 0)  left  = 0.f;
            float right = __shfl_down(M.x, 1);  if (wi == 15) right = 0.f;
            float win[6] = {left, M.x, M.y, M.z, M.w, right};
            #pragma unroll
            for (int o = 0; o < 2; ++o) {
                const int kh = j - o;           // input row = (h0+o) + kh - 1
                if (kh >= 0 && kh <= 2) {
                    #pragma unroll
                    for (int co = 0; co < CC; ++co) {
                        float wa = cw[((co * CC + ch) * 3 + kh) * 3 + 0];
                        float wb = cw[((co * CC + ch) * 3 + kh) * 3 + 1];
                        float wc = cw[((co * CC + ch) * 3 + kh) * 3 + 2];
                        #pragma unroll
                        for (int k = 0; k < 4; ++k)
                            acc[o][co][k] += win[k] * wa + win[k + 1] * wb + win[k + 2] * wc;
                    }
                }
            }
        }
    }

    float e = ec[t];
    int tr = tarr[t];
    #pragma unroll
    for (int o = 0; o < 2; ++o)
        #pragma unroll
        for (int co = 0; co < CC; ++co) {
            float b = temb[tr * CC + co];
            ushort4 v;
            v.x = f2bf(e * (acc[o][co][0] + b));
            v.y = f2bf(e * (acc[o][co][1] + b));
            v.z = f2bf(e * (acc[o][co][2] + b));
            v.w = f2bf(e * (acc[o][co][3] + b));
            *(ushort4*)(A + (size_t)t * CHW + co * HW + (h0 + o) * WW + w0) = v;
        }
}

// S[ch,pos] = sum of A over the chunk's CLEN t's (f32 accumulate from bf16)
__global__ __launch_bounds__(256) void chunk_sum_kernel(const unsigned short* __restrict__ A,
                                                        float4* __restrict__ S) {
    int ch = blockIdx.x / 12;                   // block-uniform
    int pos4 = (blockIdx.x % 12) * 256 + threadIdx.x;
    const unsigned short* p = A + (size_t)ch * CLEN * CHW + pos4 * 4;
    float4 acc = make_float4(0.f, 0.f, 0.f, 0.f);
    #pragma unroll
    for (int i = 0; i < CLEN; ++i) {
        ushort4 u = *(const ushort4*)(p + (size_t)i * CHW);
        acc.x += bf2f(u.x); acc.y += bf2f(u.y); acc.z += bf2f(u.z); acc.w += bf2f(u.w);
    }
    S[(size_t)ch * CHW4 + pos4] = acc;
}

// xt_next[t] = ar[t]*xT + epc[t]*(inline chunk-offset + local running sum)
// The exclusive chunk offset is computed inline: sum of S[j][pos4] for j < ch
// (column-local, coalesced, L2-resident) -- no scan dispatch needed.
// OUT_BF16: write bf16 state X_ws[t+1] (iters 1,2). Else f32 d_out[t+1] (iter 3).
template <bool OUT_BF16>
__global__ __launch_bounds__(256) void final_kernel(const unsigned short* __restrict__ A,
                                                    const float4* __restrict__ S,
                                                    const float4* __restrict__ xT,
                                                    const float* __restrict__ ar,
                                                    const float* __restrict__ epc,
                                                    void* __restrict__ out_v) {
    int ch = blockIdx.x / 12;                   // block-uniform
    int pos4 = (blockIdx.x % 12) * 256 + threadIdx.x;

    // inline exclusive prefix over chunk sums (4 independent partials for ILP)
    float4 a0 = make_float4(0.f, 0.f, 0.f, 0.f);
    float4 a1 = make_float4(0.f, 0.f, 0.f, 0.f);
    float4 a2 = make_float4(0.f, 0.f, 0.f, 0.f);
    float4 a3 = make_float4(0.f, 0.f, 0.f, 0.f);
    int j = 0;
    for (; j + 4 <= ch; j += 4) {               // block-uniform trip count
        float4 v0 = S[(size_t)(j + 0) * CHW4 + pos4];
        float4 v1 = S[(size_t)(j + 1) * CHW4 + pos4];
        float4 v2 = S[(size_t)(j + 2) * CHW4 + pos4];
        float4 v3 = S[(size_t)(j + 3) * CHW4 + pos4];
        a0.x += v0.x; a0.y += v0.y; a0.z += v0.z; a0.w += v0.w;
        a1.x += v1.x; a1.y += v1.y; a1.z += v1.z; a1.w += v1.w;
        a2.x += v2.x; a2.y += v2.y; a2.z += v2.z; a2.w += v2.w;
        a3.x += v3.x; a3.y += v3.y; a3.z += v3.z; a3.w += v3.w;
    }
    for (; j < ch; ++j) {
        float4 v = S[(size_t)j * CHW4 + pos4];
        a0.x += v.x; a0.y += v.y; a0.z += v.z; a0.w += v.w;
    }
    float4 acc = make_float4((a0.x + a1.x) + (a2.x + a3.x),
                             (a0.y + a1.y) + (a2.y + a3.y),
                             (a0.z + a1.z) + (a2.z + a3.z),
                             (a0.w + a1.w) + (a2.w + a3.w));

    float4 xv = xT[pos4];
    const unsigned short* p = A + (size_t)ch * CLEN * CHW + pos4 * 4;
    float4* qf = (float4*)out_v + (size_t)(ch * CLEN + 1) * CHW4 + pos4;
    unsigned short* qb = (unsigned short*)out_v + ((size_t)(ch * CLEN + 1) * CHW4 + pos4) * 4;
    #pragma unroll
    for (int i = 0; i < CLEN; ++i) {
        int t = ch * CLEN + i;                  // block-uniform -> s_load
        ushort4 u = *(const ushort4*)(p + (size_t)i * CHW);
        acc.x += bf2f(u.x); acc.y += bf2f(u.y); acc.z += bf2f(u.z); acc.w += bf2f(u.w);
        float a = ar[t], e = epc[t];
        float4 r = make_float4(a * xv.x + e * acc.x, a * xv.y + e * acc.y,
                               a * xv.z + e * acc.z, a * xv.w + e * acc.w);
        if (OUT_BF16) {
            ushort4 ub;
            ub.x = f2bf(r.x); ub.y = f2bf(r.y); ub.z = f2bf(r.z); ub.w = f2bf(r.w);
            *(ushort4*)(qb + (size_t)i * CHW) = ub;
        } else {
            qf[(size_t)i * CHW4] = r;
        }
    }
}

extern "C" void kernel_launch(void* const* d_in, const int* in_sizes, int n_in,
                              void* d_out, int out_size, void* d_ws, size_t ws_size,
                              hipStream_t stream) {
    const float* x    = (const float*)d_in[0];   // (T+1, C, H, W)
    const int*   tarr = (const int*)  d_in[1];   // (T,)
    const float* ar   = (const float*)d_in[2];   // (T,1,1,1)
    const float* ec   = (const float*)d_in[3];   // (T,1,1,1)
    const float* epc  = (const float*)d_in[4];   // (T,1,1,1)
    const float* cw   = (const float*)d_in[5];   // (C,C,3,3)
    const float* temb = (const float*)d_in[6];   // (T,C)
    float* out = (float*)d_out;                  // (T+1, C, H, W)

    unsigned short* A = (unsigned short*)d_ws;      // TT*CHW bf16 (24.6 MB)
    float* S = (float*)(A + (size_t)TT * CHW);      // NCHUNK*CHW f32 (2.46 MB)
    unsigned short* X = (unsigned short*)(S + (size_t)NCHUNK * CHW);  // (TT+1)*CHW bf16 state

    // iter 1: f32 x in -> bf16 X state out; tail blocks copy out[0]=xT, X[0]=bf16(xT)
    conv_kernel<false, true><<<NCONVB + 12, 256, 0, stream>>>(x, cw, temb, tarr, ec, A, out, X);
    chunk_sum_kernel<<<NCHUNK * 12, 256, 0, stream>>>(A, (float4*)S);
    final_kernel<true><<<NCHUNK * 12, 256, 0, stream>>>(A, (const float4*)S,
                                                        (const float4*)x, ar, epc, X);

    // iter 2: bf16 X in -> bf16 X out
    conv_kernel<true, false><<<NCONVB, 256, 0, stream>>>(X, cw, temb, tarr, ec, A, out, X);
    chunk_sum_kernel<<<NCHUNK * 12, 256, 0, stream>>>(A, (float4*)S);
    final_kernel<true><<<NCHUNK * 12, 256, 0, stream>>>(A, (const float4*)S,
                                                        (const float4*)x, ar, epc, X);

    // iter 3: bf16 X in -> f32 d_out
    conv_kernel<true, false><<<NCONVB, 256, 0, stream>>>(X, cw, temb, tarr, ec, A, out, X);
    chunk_sum_kernel<<<NCHUNK * 12, 256, 0, stream>>>(A, (float4*)S);
    final_kernel<false><<<NCHUNK * 12, 256, 0, stream>>>(A, (const float4*)S,
                                                         (const float4*)x, ar, epc, out);
}